// Round 1
// baseline (332.280 us; speedup 1.0000x reference)
//
#include <hip/hip_runtime.h>
#include <hip/hip_bf16.h>

#define PAD_V 8192
#define H1 512
#define H2 64
#define B_SZ 32
#define K_SZ 32
#define L_SZ 128
#define BAGS 4          // bags per block in embed/MLP kernel
#define QBLOCKS (B_SZ / BAGS)            // 8
#define PBLOCKS ((B_SZ * K_SZ) / BAGS)   // 256

// ---------------------------------------------------------------------------
// Kernel 1: embedding_bag_mean + prelu(a0) + [H1->H2 prelu(a1)] + [H2->H2 prelu(a2)]
// blocks 0..7: query path (32 bags); blocks 8..263: poi path (1024 bags)
// ---------------------------------------------------------------------------
__global__ __launch_bounds__(256) void emb_mlp_kernel(
    const int* __restrict__ qbf, const int* __restrict__ pbf,
    const float* __restrict__ codebook,
    const float* __restrict__ qW1, const float* __restrict__ qb1,
    const float* __restrict__ qW2, const float* __restrict__ qb2,
    const float* __restrict__ pW1, const float* __restrict__ pb1,
    const float* __restrict__ pW2, const float* __restrict__ pb2,
    const float* __restrict__ qa0p, const float* __restrict__ qa1p, const float* __restrict__ qa2p,
    const float* __restrict__ pa0p, const float* __restrict__ pa1p, const float* __restrict__ pa2p,
    float* __restrict__ qh_out, float* __restrict__ ph_out)
{
    const int tid = threadIdx.x;
    const bool is_q = (blockIdx.x < QBLOCKS);

    const int*   idx_base;
    int          bag0;
    const float *W1, *b1, *W2, *b2;
    float a0, a1, a2;
    float* out;
    if (is_q) {
        idx_base = qbf; bag0 = blockIdx.x * BAGS;
        W1 = qW1; b1 = qb1; W2 = qW2; b2 = qb2;
        a0 = *qa0p; a1 = *qa1p; a2 = *qa2p;
        out = qh_out;
    } else {
        idx_base = pbf; bag0 = (blockIdx.x - QBLOCKS) * BAGS;
        W1 = pW1; b1 = pb1; W2 = pW2; b2 = pb2;
        a0 = *pa0p; a1 = *pa1p; a2 = *pa2p;
        out = ph_out;
    }

    __shared__ int   s_idx[BAGS][L_SZ];
    __shared__ int   s_cnt[BAGS];
    __shared__ float s_he[BAGS][H1];       // post-prelu embedding, 8 KB
    __shared__ float s_h2[BAGS][H2];       // hidden layer 1 out

    // stage indices
    for (int t = tid; t < BAGS * L_SZ; t += 256) {
        int bag = t >> 7, l = t & 127;
        s_idx[bag][l] = idx_base[(bag0 + bag) * L_SZ + l];
    }
    __syncthreads();
    if (tid < BAGS) {
        int c = 0;
        for (int l = 0; l < L_SZ; l++) c += (s_idx[tid][l] != PAD_V);
        s_cnt[tid] = c;
    }
    __syncthreads();

    // embedding bag gather-sum: each thread owns 2 consecutive columns (float2)
    const float2* cb2 = (const float2*)codebook;
    for (int bag = 0; bag < BAGS; bag++) {
        float ax = 0.f, ay = 0.f;
        #pragma unroll 8
        for (int l = 0; l < L_SZ; l++) {
            int v = s_idx[bag][l];
            if (v != PAD_V) {
                float2 r = cb2[(v << 8) + tid];   // v * 256 float2 per row
                ax += r.x; ay += r.y;
            }
        }
        int cnt = s_cnt[bag];
        float inv = (cnt > 0) ? 1.0f / (float)cnt : 0.0f;
        float e0 = ax * inv, e1 = ay * inv;
        e0 = (e0 >= 0.f) ? e0 : a0 * e0;
        e1 = (e1 >= 0.f) ? e1 : a0 * e1;
        s_he[bag][2 * tid]     = e0;
        s_he[bag][2 * tid + 1] = e1;
    }
    __syncthreads();

    // layer 1: (BAGS x H1) @ (H1 x H2). wave w == bag w; j = lane
    const int bag = tid >> 6;
    const int j   = tid & 63;
    float s = 0.f;
    #pragma unroll 8
    for (int i = 0; i < H1; i++) {
        s += s_he[bag][i] * W1[i * H2 + j];   // LDS broadcast * coalesced global
    }
    s += b1[j];
    s = (s >= 0.f) ? s : a1 * s;
    s_h2[bag][j] = s;
    __syncthreads();

    // layer 2: (BAGS x H2) @ (H2 x H2)
    float s2 = 0.f;
    #pragma unroll 8
    for (int i = 0; i < H2; i++) {
        s2 += s_h2[bag][i] * W2[i * H2 + j];
    }
    s2 += b2[j];
    s2 = (s2 >= 0.f) ? s2 : a2 * s2;
    out[(bag0 + bag) * H2 + j] = s2;
}

// ---------------------------------------------------------------------------
// Kernel 2: intersection (bitmap) + eval dots + text_sim + max-norm + epilogue
// one block per b
// ---------------------------------------------------------------------------
__global__ __launch_bounds__(256) void score_kernel(
    const int* __restrict__ qbf, const int* __restrict__ pbf,
    const float* __restrict__ qloc, const float* __restrict__ ploc,
    const float* __restrict__ q_eval, const float* __restrict__ p_eval,
    const float* __restrict__ qh_ws, const float* __restrict__ ph_ws,
    const float* __restrict__ ind_ap, const float* __restrict__ ap,
    const float* __restrict__ bp, const float* __restrict__ cp,
    const float* __restrict__ dp,
    float* __restrict__ out)
{
    const int b   = blockIdx.x;
    const int tid = threadIdx.x;

    __shared__ unsigned int bm[K_SZ][256];   // 8192-bit membership per k, 32 KB
    __shared__ int   s_q[L_SZ];
    __shared__ float s_qh[H2];
    __shared__ float s_ph[K_SZ][H2 + 1];     // +1 pad: 8 lanes share a k-row
    __shared__ float s_part[256];
    __shared__ float s_text[K_SZ];
    __shared__ float s_mx;

    for (int t = tid; t < K_SZ * 256; t += 256) ((unsigned int*)bm)[t] = 0u;
    if (tid < L_SZ) s_q[tid] = qbf[b * L_SZ + tid];
    if (tid < H2)   s_qh[tid] = qh_ws[b * H2 + tid];
    for (int t = tid; t < K_SZ * H2; t += 256)
        s_ph[t >> 6][t & 63] = ph_ws[(b * K_SZ + (t >> 6)) * H2 + (t & 63)];
    __syncthreads();

    // build per-k membership bitmaps from poi bloom filters
    for (int t = tid; t < K_SZ * L_SZ; t += 256) {
        int k = t >> 7, jj = t & 127;
        int v = pbf[(b * K_SZ + k) * L_SZ + jj];
        if ((unsigned)v < (unsigned)PAD_V)
            atomicOr(&bm[k][v >> 5], 1u << (v & 31));
    }
    __syncthreads();

    const float ind_a = *ind_ap;

    // each thread: one k (tid>>3), 16 l values
    const int k  = tid >> 3;
    const int l0 = (tid & 7) * 16;
    float local = 0.f;
    for (int r = 0; r < 16; r++) {
        int l = l0 + r;
        int v = s_q[l];
        bool hit = ((unsigned)v < (unsigned)PAD_V) &&
                   ((bm[k][v >> 5] >> (v & 31)) & 1u);
        if (hit) {
            const float* qr = q_eval + v * H2;
            const float* pr = p_eval + v * H2;
            float qd = 0.f, pd = 0.f;
            #pragma unroll 8
            for (int i = 0; i < H2; i++) {
                qd += s_qh[i] * qr[i];
                pd += s_ph[k][i] * pr[i];
            }
            qd = (qd >= 0.f) ? qd : ind_a * qd;
            pd = (pd >= 0.f) ? pd : ind_a * pd;
            local += (qd + 1.f) * (pd + 1.f);
        }
    }
    s_part[tid] = local;
    __syncthreads();

    if (tid < K_SZ) {
        float s = 0.f;
        for (int r = 0; r < 8; r++) s += s_part[tid * 8 + r];
        s_text[tid] = s;
    }
    __syncthreads();
    if (tid == 0) {
        float m = s_text[0];
        for (int kk = 1; kk < K_SZ; kk++) m = fmaxf(m, s_text[kk]);
        s_mx = m;
    }
    __syncthreads();

    if (tid < K_SZ) {
        const int kk = tid;
        float qx = qloc[b * 2], qy = qloc[b * 2 + 1];
        float px = ploc[(b * K_SZ + kk) * 2];
        float py = ploc[(b * K_SZ + kk) * 2 + 1];
        float dx = qx - px, dy = qy - py;
        float dist = sqrtf(dx * dx + dy * dy);
        float ds = -logf(dist + 1.0f);
        float mx = s_mx;
        float ts = (2.0f * s_text[kk] - mx) / (mx + 1e-6f);
        float A = *ap, Bb = *bp, C = *cp, D = *dp;
        float sig = 1.0f / (1.0f + expf(-(A * ts + Bb)));
        out[b * K_SZ + kk] = (C - sig) * (ds - D);
    }
}

extern "C" void kernel_launch(void* const* d_in, const int* in_sizes, int n_in,
                              void* d_out, int out_size, void* d_ws, size_t ws_size,
                              hipStream_t stream) {
    const int*   qbf      = (const int*)d_in[0];
    const int*   pbf      = (const int*)d_in[1];
    const float* qloc     = (const float*)d_in[2];
    const float* ploc     = (const float*)d_in[3];
    const float* codebook = (const float*)d_in[4];
    const float* qW1      = (const float*)d_in[5];
    const float* qb1      = (const float*)d_in[6];
    const float* qW2      = (const float*)d_in[7];
    const float* qb2      = (const float*)d_in[8];
    const float* pW1      = (const float*)d_in[9];
    const float* pb1      = (const float*)d_in[10];
    const float* pW2      = (const float*)d_in[11];
    const float* pb2      = (const float*)d_in[12];
    const float* q_eval   = (const float*)d_in[13];
    const float* p_eval   = (const float*)d_in[14];
    const float* qa0      = (const float*)d_in[15];
    const float* qa1      = (const float*)d_in[16];
    const float* qa2      = (const float*)d_in[17];
    const float* pa0      = (const float*)d_in[18];
    const float* pa1      = (const float*)d_in[19];
    const float* pa2      = (const float*)d_in[20];
    const float* ind_a    = (const float*)d_in[21];
    const float* a        = (const float*)d_in[22];
    const float* bsc      = (const float*)d_in[23];
    const float* c        = (const float*)d_in[24];
    const float* d        = (const float*)d_in[25];

    float* qh = (float*)d_ws;                 // 32*64 f32
    float* ph = qh + B_SZ * H2;               // 1024*64 f32

    emb_mlp_kernel<<<QBLOCKS + PBLOCKS, 256, 0, stream>>>(
        qbf, pbf, codebook,
        qW1, qb1, qW2, qb2, pW1, pb1, pW2, pb2,
        qa0, qa1, qa2, pa0, pa1, pa2,
        qh, ph);

    score_kernel<<<B_SZ, 256, 0, stream>>>(
        qbf, pbf, qloc, ploc, q_eval, p_eval,
        qh, ph, ind_a, a, bsc, c, d,
        (float*)d_out);
}

// Round 2
// 158.686 us; speedup vs baseline: 2.0939x; 2.0939x over previous
//
#include <hip/hip_runtime.h>
#include <hip/hip_bf16.h>

#define PAD_V 8192
#define H1 512
#define H2 64
#define B_SZ 32
#define K_SZ 32
#define L_SZ 128

// ---------------------------------------------------------------------------
// Kernel 1: one bag per block. embedding_bag_mean + prelu(a0) + MLP.
// blocks 0..31: query bags; blocks 32..1055: poi bags.
// ---------------------------------------------------------------------------
__global__ __launch_bounds__(256) void emb_mlp_kernel(
    const int* __restrict__ qbf, const int* __restrict__ pbf,
    const float* __restrict__ codebook,
    const float* __restrict__ qW1, const float* __restrict__ qb1,
    const float* __restrict__ qW2, const float* __restrict__ qb2,
    const float* __restrict__ pW1, const float* __restrict__ pb1,
    const float* __restrict__ pW2, const float* __restrict__ pb2,
    const float* __restrict__ qa0p, const float* __restrict__ qa1p, const float* __restrict__ qa2p,
    const float* __restrict__ pa0p, const float* __restrict__ pa1p, const float* __restrict__ pa2p,
    float* __restrict__ qh_out, float* __restrict__ ph_out)
{
    const int tid = threadIdx.x;
    const bool is_q = (blockIdx.x < B_SZ);

    const int* idx_base;
    int bag;
    const float *W1, *b1, *W2, *b2;
    float a0, a1, a2;
    float* out;
    if (is_q) {
        idx_base = qbf; bag = blockIdx.x;
        W1 = qW1; b1 = qb1; W2 = qW2; b2 = qb2;
        a0 = *qa0p; a1 = *qa1p; a2 = *qa2p;
        out = qh_out;
    } else {
        idx_base = pbf; bag = blockIdx.x - B_SZ;
        W1 = pW1; b1 = pb1; W2 = pW2; b2 = pb2;
        a0 = *pa0p; a1 = *pa1p; a2 = *pa2p;
        out = ph_out;
    }

    __shared__ int   s_idx[L_SZ];
    __shared__ int   s_cntp[4];
    __shared__ float s_red[128][4];   // half-1 partials
    __shared__ float s_x[H1];         // post-prelu mean embedding
    __shared__ float s_p1[4][H2];     // MLP partials
    __shared__ float s_h1[H2];

    // stage indices (128 ints)
    if (tid < L_SZ) s_idx[tid] = idx_base[bag * L_SZ + tid];
    __syncthreads();

    // count non-PAD via per-wave ballots
    {
        int vv = (tid < L_SZ) ? s_idx[tid] : PAD_V;
        unsigned long long bal = __ballot(vv != PAD_V);
        if ((tid & 63) == 0) s_cntp[tid >> 6] = __popcll(bal);
    }

    // gather: thread = (half h = tid>>7) x (float4 group g = tid&127)
    // each thread: 64 unconditional float4 loads, masked by FMA weight.
    const int g = tid & 127;
    const int h = tid >> 7;
    const float4* cb4 = (const float4*)codebook;
    float ax = 0.f, ay = 0.f, az = 0.f, aw = 0.f;
    #pragma unroll 8
    for (int l = 0; l < 64; l++) {
        int v = s_idx[h * 64 + l];
        float m = (v != PAD_V) ? 1.0f : 0.0f;
        float4 r = cb4[(size_t)v * 128 + g];   // row v, 16B chunk g
        ax = fmaf(m, r.x, ax);
        ay = fmaf(m, r.y, ay);
        az = fmaf(m, r.z, az);
        aw = fmaf(m, r.w, aw);
    }
    if (h == 1) { s_red[g][0] = ax; s_red[g][1] = ay; s_red[g][2] = az; s_red[g][3] = aw; }
    __syncthreads();
    if (h == 0) {
        int cnt = s_cntp[0] + s_cntp[1] + s_cntp[2] + s_cntp[3];
        float inv = (cnt > 0) ? 1.0f / (float)cnt : 0.0f;
        float e0 = (ax + s_red[g][0]) * inv;
        float e1 = (ay + s_red[g][1]) * inv;
        float e2 = (az + s_red[g][2]) * inv;
        float e3 = (aw + s_red[g][3]) * inv;
        s_x[4 * g + 0] = (e0 >= 0.f) ? e0 : a0 * e0;
        s_x[4 * g + 1] = (e1 >= 0.f) ? e1 : a0 * e1;
        s_x[4 * g + 2] = (e2 >= 0.f) ? e2 : a0 * e2;
        s_x[4 * g + 3] = (e3 >= 0.f) ? e3 : a0 * e3;
    }
    __syncthreads();

    // layer 1: j = tid&63, i-chunk = tid>>6 (128 i's each)
    const int j  = tid & 63;
    const int ch = tid >> 6;
    {
        const int i0 = ch * 128;
        float s = 0.f;
        #pragma unroll 8
        for (int i = 0; i < 128; i++) {
            s = fmaf(s_x[i0 + i], W1[(i0 + i) * H2 + j], s);
        }
        s_p1[ch][j] = s;
    }
    __syncthreads();
    if (tid < H2) {
        float s = s_p1[0][tid] + s_p1[1][tid] + s_p1[2][tid] + s_p1[3][tid] + b1[tid];
        s_h1[tid] = (s >= 0.f) ? s : a1 * s;
    }
    __syncthreads();

    // layer 2: j = tid&63, i-chunk = tid>>6 (16 i's each)
    {
        const int i0 = ch * 16;
        float s = 0.f;
        #pragma unroll
        for (int i = 0; i < 16; i++) {
            s = fmaf(s_h1[i0 + i], W2[(i0 + i) * H2 + j], s);
        }
        s_p1[ch][j] = s;
    }
    __syncthreads();
    if (tid < H2) {
        float s = s_p1[0][tid] + s_p1[1][tid] + s_p1[2][tid] + s_p1[3][tid] + b2[tid];
        s = (s >= 0.f) ? s : a2 * s;
        out[bag * H2 + tid] = s;
    }
}

// ---------------------------------------------------------------------------
// Kernel 2: one block per (b,k). Bitmap intersection + cooperative eval dots.
// Writes text_sim[b*32+k] to ws.
// ---------------------------------------------------------------------------
__global__ __launch_bounds__(128) void text_sim_kernel(
    const int* __restrict__ qbf, const int* __restrict__ pbf,
    const float* __restrict__ q_eval, const float* __restrict__ p_eval,
    const float* __restrict__ qh_ws, const float* __restrict__ ph_ws,
    const float* __restrict__ ind_ap,
    float* __restrict__ text_out)
{
    const int blk = blockIdx.x;
    const int b   = blk >> 5;
    const int k   = blk & 31;
    const int tid = threadIdx.x;
    const int lane = tid & 63;
    const int wave = tid >> 6;

    __shared__ unsigned int bm[256];   // 8192-bit membership
    __shared__ float s_qh[H2];
    __shared__ float s_ph[H2];
    __shared__ int   s_hitv[L_SZ];
    __shared__ int   s_nh;
    __shared__ float s_wp[2];

    bm[tid] = 0u; bm[tid + 128] = 0u;
    if (tid == 0) s_nh = 0;
    if (tid < H2)  s_qh[tid] = qh_ws[b * H2 + tid];
    else           s_ph[tid - H2] = ph_ws[(b * K_SZ + k) * H2 + (tid - H2)];

    int pv = pbf[(b * K_SZ + k) * L_SZ + tid];
    if ((unsigned)pv < (unsigned)PAD_V)
        atomicOr(&bm[pv >> 5], 1u << (pv & 31));
    __syncthreads();

    // test query values, compact hits
    {
        int v = qbf[b * L_SZ + tid];
        bool hit = ((unsigned)v < (unsigned)PAD_V) &&
                   ((bm[v >> 5] >> (v & 31)) & 1u);
        if (hit) {
            int pos = atomicAdd(&s_nh, 1);
            s_hitv[pos] = v;
        }
    }
    __syncthreads();

    const int nh = s_nh;
    const float ind_a = *ind_ap;
    float local = 0.f;

    // cooperative: wave handles hit h; 64 lanes dot + butterfly reduce
    for (int hh = wave; hh < nh; hh += 2) {
        int v = s_hitv[hh];
        float qd = s_qh[lane] * q_eval[(size_t)v * H2 + lane];
        float pd = s_ph[lane] * p_eval[(size_t)v * H2 + lane];
        #pragma unroll
        for (int m = 1; m < 64; m <<= 1) {
            qd += __shfl_xor(qd, m);
            pd += __shfl_xor(pd, m);
        }
        qd = (qd >= 0.f) ? qd : ind_a * qd;
        pd = (pd >= 0.f) ? pd : ind_a * pd;
        local += (qd + 1.f) * (pd + 1.f);
    }
    if (lane == 0) s_wp[wave] = local;
    __syncthreads();
    if (tid == 0) text_out[blk] = s_wp[0] + s_wp[1];
}

// ---------------------------------------------------------------------------
// Kernel 3: epilogue — per-b max, normalize, sigmoid, distance term.
// ---------------------------------------------------------------------------
__global__ __launch_bounds__(1024) void epilogue_kernel(
    const float* __restrict__ text_ws,
    const float* __restrict__ qloc, const float* __restrict__ ploc,
    const float* __restrict__ ap, const float* __restrict__ bp,
    const float* __restrict__ cp, const float* __restrict__ dp,
    float* __restrict__ out)
{
    const int t = threadIdx.x;   // 0..1023
    const int b = t >> 5;
    __shared__ float s_text[B_SZ * K_SZ];
    s_text[t] = text_ws[t];
    __syncthreads();

    float mx = s_text[b * K_SZ];
    #pragma unroll
    for (int i = 1; i < K_SZ; i++) mx = fmaxf(mx, s_text[b * K_SZ + i]);

    float qx = qloc[b * 2], qy = qloc[b * 2 + 1];
    float px = ploc[t * 2], py = ploc[t * 2 + 1];
    float dx = qx - px, dy = qy - py;
    float dist = sqrtf(dx * dx + dy * dy);
    float ds = -logf(dist + 1.0f);

    float ts = (2.0f * s_text[t] - mx) / (mx + 1e-6f);
    float A = *ap, Bb = *bp, C = *cp, D = *dp;
    float sig = 1.0f / (1.0f + expf(-(A * ts + Bb)));
    out[t] = (C - sig) * (ds - D);
}

extern "C" void kernel_launch(void* const* d_in, const int* in_sizes, int n_in,
                              void* d_out, int out_size, void* d_ws, size_t ws_size,
                              hipStream_t stream) {
    const int*   qbf      = (const int*)d_in[0];
    const int*   pbf      = (const int*)d_in[1];
    const float* qloc     = (const float*)d_in[2];
    const float* ploc     = (const float*)d_in[3];
    const float* codebook = (const float*)d_in[4];
    const float* qW1      = (const float*)d_in[5];
    const float* qb1      = (const float*)d_in[6];
    const float* qW2      = (const float*)d_in[7];
    const float* qb2      = (const float*)d_in[8];
    const float* pW1      = (const float*)d_in[9];
    const float* pb1      = (const float*)d_in[10];
    const float* pW2      = (const float*)d_in[11];
    const float* pb2      = (const float*)d_in[12];
    const float* q_eval   = (const float*)d_in[13];
    const float* p_eval   = (const float*)d_in[14];
    const float* qa0      = (const float*)d_in[15];
    const float* qa1      = (const float*)d_in[16];
    const float* qa2      = (const float*)d_in[17];
    const float* pa0      = (const float*)d_in[18];
    const float* pa1      = (const float*)d_in[19];
    const float* pa2      = (const float*)d_in[20];
    const float* ind_a    = (const float*)d_in[21];
    const float* a        = (const float*)d_in[22];
    const float* bsc      = (const float*)d_in[23];
    const float* c        = (const float*)d_in[24];
    const float* d        = (const float*)d_in[25];

    float* qh   = (float*)d_ws;                   // 32*64
    float* ph   = qh + B_SZ * H2;                 // 1024*64
    float* text = ph + B_SZ * K_SZ * H2;          // 1024

    emb_mlp_kernel<<<B_SZ + B_SZ * K_SZ, 256, 0, stream>>>(
        qbf, pbf, codebook,
        qW1, qb1, qW2, qb2, pW1, pb1, pW2, pb2,
        qa0, qa1, qa2, pa0, pa1, pa2,
        qh, ph);

    text_sim_kernel<<<B_SZ * K_SZ, 128, 0, stream>>>(
        qbf, pbf, q_eval, p_eval, qh, ph, ind_a, text);

    epilogue_kernel<<<1, B_SZ * K_SZ, 0, stream>>>(
        text, qloc, ploc, a, bsc, c, d, (float*)d_out);
}

// Round 3
// 155.573 us; speedup vs baseline: 2.1358x; 1.0200x over previous
//
#include <hip/hip_runtime.h>
#include <hip/hip_bf16.h>

#define PAD_V 8192
#define H1 512
#define H2 64
#define B_SZ 32
#define K_SZ 32
#define L_SZ 128

// ---------------------------------------------------------------------------
// Kernel 1: one bag per block, 512 threads (8 waves -> ~full occupancy).
// embedding_bag_mean + prelu(a0) + [H1->H2 prelu(a1)] + [H2->H2 prelu(a2)]
// blocks 0..31: query bags; blocks 32..1055: poi bags.
// ---------------------------------------------------------------------------
__global__ __launch_bounds__(512, 8) void emb_mlp_kernel(
    const int* __restrict__ qbf, const int* __restrict__ pbf,
    const float* __restrict__ codebook,
    const float* __restrict__ qW1, const float* __restrict__ qb1,
    const float* __restrict__ qW2, const float* __restrict__ qb2,
    const float* __restrict__ pW1, const float* __restrict__ pb1,
    const float* __restrict__ pW2, const float* __restrict__ pb2,
    const float* __restrict__ qa0p, const float* __restrict__ qa1p, const float* __restrict__ qa2p,
    const float* __restrict__ pa0p, const float* __restrict__ pa1p, const float* __restrict__ pa2p,
    float* __restrict__ qh_out, float* __restrict__ ph_out)
{
    const int tid = threadIdx.x;
    const bool is_q = (blockIdx.x < B_SZ);

    const int* idx_base;
    int bag;
    const float *W1, *b1, *W2, *b2;
    float a0, a1, a2;
    float* out;
    if (is_q) {
        idx_base = qbf; bag = blockIdx.x;
        W1 = qW1; b1 = qb1; W2 = qW2; b2 = qb2;
        a0 = *qa0p; a1 = *qa1p; a2 = *qa2p;
        out = qh_out;
    } else {
        idx_base = pbf; bag = blockIdx.x - B_SZ;
        W1 = pW1; b1 = pb1; W2 = pW2; b2 = pb2;
        a0 = *pa0p; a1 = *pa1p; a2 = *pa2p;
        out = ph_out;
    }

    __shared__ int   s_idx[L_SZ];
    __shared__ int   s_cntp[2];
    __shared__ float s_red[3][L_SZ][4];   // quarters 1..3 partials, 6 KB
    __shared__ float s_x[H1];             // post-prelu mean embedding
    __shared__ float s_p1[8][H2];         // MLP partials, 2 KB
    __shared__ float s_h1[H2];

    // stage indices (128 ints)
    if (tid < L_SZ) s_idx[tid] = idx_base[bag * L_SZ + tid];
    __syncthreads();

    // count non-PAD via ballots on waves 0,1 (tid<128)
    if (tid < L_SZ) {
        unsigned long long bal = __ballot(s_idx[tid] != PAD_V);
        if ((tid & 63) == 0) s_cntp[tid >> 6] = __popcll(bal);
    }

    // gather: quarter q = tid>>7 owns 32 rows; g = tid&127 is the 16B chunk
    const int g = tid & 127;
    const int q = tid >> 7;
    const float4* cb4 = (const float4*)codebook;
    float ax = 0.f, ay = 0.f, az = 0.f, aw = 0.f;
    #pragma unroll 8
    for (int l = 0; l < 32; l++) {
        int v = s_idx[q * 32 + l];
        float m = (v != PAD_V) ? 1.0f : 0.0f;
        float4 r = cb4[(size_t)v * 128 + g];
        ax = fmaf(m, r.x, ax);
        ay = fmaf(m, r.y, ay);
        az = fmaf(m, r.z, az);
        aw = fmaf(m, r.w, aw);
    }
    if (q != 0) {
        s_red[q - 1][g][0] = ax; s_red[q - 1][g][1] = ay;
        s_red[q - 1][g][2] = az; s_red[q - 1][g][3] = aw;
    }
    __syncthreads();
    if (q == 0) {
        int cnt = s_cntp[0] + s_cntp[1];
        float inv = (cnt > 0) ? 1.0f / (float)cnt : 0.0f;
        float e0 = (ax + s_red[0][g][0] + s_red[1][g][0] + s_red[2][g][0]) * inv;
        float e1 = (ay + s_red[0][g][1] + s_red[1][g][1] + s_red[2][g][1]) * inv;
        float e2 = (az + s_red[0][g][2] + s_red[1][g][2] + s_red[2][g][2]) * inv;
        float e3 = (aw + s_red[0][g][3] + s_red[1][g][3] + s_red[2][g][3]) * inv;
        s_x[4 * g + 0] = (e0 >= 0.f) ? e0 : a0 * e0;
        s_x[4 * g + 1] = (e1 >= 0.f) ? e1 : a0 * e1;
        s_x[4 * g + 2] = (e2 >= 0.f) ? e2 : a0 * e2;
        s_x[4 * g + 3] = (e3 >= 0.f) ? e3 : a0 * e3;
    }
    __syncthreads();

    // layer 1: j = tid&63, i-chunk = tid>>6 (8 chunks x 64 i's)
    const int j  = tid & 63;
    const int ch = tid >> 6;
    {
        const int i0 = ch * 64;
        float s = 0.f;
        #pragma unroll 8
        for (int i = 0; i < 64; i++) {
            s = fmaf(s_x[i0 + i], W1[(i0 + i) * H2 + j], s);
        }
        s_p1[ch][j] = s;
    }
    __syncthreads();
    if (tid < H2) {
        float s = b1[tid];
        #pragma unroll
        for (int r = 0; r < 8; r++) s += s_p1[r][tid];
        s_h1[tid] = (s >= 0.f) ? s : a1 * s;
    }
    __syncthreads();

    // layer 2: 8 chunks x 8 i's
    {
        const int i0 = ch * 8;
        float s = 0.f;
        #pragma unroll
        for (int i = 0; i < 8; i++) {
            s = fmaf(s_h1[i0 + i], W2[(i0 + i) * H2 + j], s);
        }
        s_p1[ch][j] = s;
    }
    __syncthreads();
    if (tid < H2) {
        float s = b2[tid];
        #pragma unroll
        for (int r = 0; r < 8; r++) s += s_p1[r][tid];
        s = (s >= 0.f) ? s : a2 * s;
        out[bag * H2 + tid] = s;
    }
}

// ---------------------------------------------------------------------------
// Kernel 2: one block per (b,k). Bitmap intersection + cooperative eval dots.
// ---------------------------------------------------------------------------
__global__ __launch_bounds__(128) void text_sim_kernel(
    const int* __restrict__ qbf, const int* __restrict__ pbf,
    const float* __restrict__ q_eval, const float* __restrict__ p_eval,
    const float* __restrict__ qh_ws, const float* __restrict__ ph_ws,
    const float* __restrict__ ind_ap,
    float* __restrict__ text_out)
{
    const int blk = blockIdx.x;
    const int b   = blk >> 5;
    const int k   = blk & 31;
    const int tid = threadIdx.x;
    const int lane = tid & 63;
    const int wave = tid >> 6;

    __shared__ unsigned int bm[256];   // 8192-bit membership
    __shared__ float s_qh[H2];
    __shared__ float s_ph[H2];
    __shared__ int   s_hitv[L_SZ];
    __shared__ int   s_nh;
    __shared__ float s_wp[2];

    bm[tid] = 0u; bm[tid + 128] = 0u;
    if (tid == 0) s_nh = 0;
    if (tid < H2)  s_qh[tid] = qh_ws[b * H2 + tid];
    else           s_ph[tid - H2] = ph_ws[(b * K_SZ + k) * H2 + (tid - H2)];

    int pv = pbf[(b * K_SZ + k) * L_SZ + tid];
    if ((unsigned)pv < (unsigned)PAD_V)
        atomicOr(&bm[pv >> 5], 1u << (pv & 31));
    __syncthreads();

    // test query values, compact hits
    {
        int v = qbf[b * L_SZ + tid];
        bool hit = ((unsigned)v < (unsigned)PAD_V) &&
                   ((bm[v >> 5] >> (v & 31)) & 1u);
        if (hit) {
            int pos = atomicAdd(&s_nh, 1);
            s_hitv[pos] = v;
        }
    }
    __syncthreads();

    const int nh = s_nh;
    const float ind_a = *ind_ap;
    float local = 0.f;

    for (int hh = wave; hh < nh; hh += 2) {
        int v = s_hitv[hh];
        float qd = s_qh[lane] * q_eval[(size_t)v * H2 + lane];
        float pd = s_ph[lane] * p_eval[(size_t)v * H2 + lane];
        #pragma unroll
        for (int m = 1; m < 64; m <<= 1) {
            qd += __shfl_xor(qd, m);
            pd += __shfl_xor(pd, m);
        }
        qd = (qd >= 0.f) ? qd : ind_a * qd;
        pd = (pd >= 0.f) ? pd : ind_a * pd;
        local += (qd + 1.f) * (pd + 1.f);
    }
    if (lane == 0) s_wp[wave] = local;
    __syncthreads();
    if (tid == 0) text_out[blk] = s_wp[0] + s_wp[1];
}

// ---------------------------------------------------------------------------
// Kernel 3: epilogue — one block per b (32 lanes): max, normalize, sigmoid, dist.
// ---------------------------------------------------------------------------
__global__ __launch_bounds__(64) void epilogue_kernel(
    const float* __restrict__ text_ws,
    const float* __restrict__ qloc, const float* __restrict__ ploc,
    const float* __restrict__ ap, const float* __restrict__ bp,
    const float* __restrict__ cp, const float* __restrict__ dp,
    float* __restrict__ out)
{
    const int b = blockIdx.x;
    const int t = threadIdx.x;   // 0..63, only 0..31 store
    const int kk = t & 31;

    float ts_raw = text_ws[b * K_SZ + kk];
    float mx = ts_raw;
    #pragma unroll
    for (int m = 1; m < 32; m <<= 1) mx = fmaxf(mx, __shfl_xor(mx, m));

    float qx = qloc[b * 2], qy = qloc[b * 2 + 1];
    float px = ploc[(b * K_SZ + kk) * 2];
    float py = ploc[(b * K_SZ + kk) * 2 + 1];
    float dx = qx - px, dy = qy - py;
    float dist = sqrtf(dx * dx + dy * dy);
    float ds = -logf(dist + 1.0f);

    float ts = (2.0f * ts_raw - mx) / (mx + 1e-6f);
    float A = *ap, Bb = *bp, C = *cp, D = *dp;
    float sig = 1.0f / (1.0f + expf(-(A * ts + Bb)));
    if (t < 32) out[b * K_SZ + kk] = (C - sig) * (ds - D);
}

extern "C" void kernel_launch(void* const* d_in, const int* in_sizes, int n_in,
                              void* d_out, int out_size, void* d_ws, size_t ws_size,
                              hipStream_t stream) {
    const int*   qbf      = (const int*)d_in[0];
    const int*   pbf      = (const int*)d_in[1];
    const float* qloc     = (const float*)d_in[2];
    const float* ploc     = (const float*)d_in[3];
    const float* codebook = (const float*)d_in[4];
    const float* qW1      = (const float*)d_in[5];
    const float* qb1      = (const float*)d_in[6];
    const float* qW2      = (const float*)d_in[7];
    const float* qb2      = (const float*)d_in[8];
    const float* pW1      = (const float*)d_in[9];
    const float* pb1      = (const float*)d_in[10];
    const float* pW2      = (const float*)d_in[11];
    const float* pb2      = (const float*)d_in[12];
    const float* q_eval   = (const float*)d_in[13];
    const float* p_eval   = (const float*)d_in[14];
    const float* qa0      = (const float*)d_in[15];
    const float* qa1      = (const float*)d_in[16];
    const float* qa2      = (const float*)d_in[17];
    const float* pa0      = (const float*)d_in[18];
    const float* pa1      = (const float*)d_in[19];
    const float* pa2      = (const float*)d_in[20];
    const float* ind_a    = (const float*)d_in[21];
    const float* a        = (const float*)d_in[22];
    const float* bsc      = (const float*)d_in[23];
    const float* c        = (const float*)d_in[24];
    const float* d        = (const float*)d_in[25];

    float* qh   = (float*)d_ws;                   // 32*64
    float* ph   = qh + B_SZ * H2;                 // 1024*64
    float* text = ph + B_SZ * K_SZ * H2;          // 1024

    emb_mlp_kernel<<<B_SZ + B_SZ * K_SZ, 512, 0, stream>>>(
        qbf, pbf, codebook,
        qW1, qb1, qW2, qb2, pW1, pb1, pW2, pb2,
        qa0, qa1, qa2, pa0, pa1, pa2,
        qh, ph);

    text_sim_kernel<<<B_SZ * K_SZ, 128, 0, stream>>>(
        qbf, pbf, q_eval, p_eval, qh, ph, ind_a, text);

    epilogue_kernel<<<B_SZ, 64, 0, stream>>>(
        text, qloc, ploc, a, bsc, c, d, (float*)d_out);
}